// Round 10
// baseline (681.824 us; speedup 1.0000x reference)
//
#include <hip/hip_runtime.h>
#include <hip/hip_bf16.h>

#define UF 512
#define EF 256
#define NB 64
#define NU 1024
#define NEN 1024

typedef __attribute__((ext_vector_type(8))) short short8;    // 8 bf16 (4 VGPRs)
typedef __attribute__((ext_vector_type(4))) float floatx4;   // MFMA acc / ext-vector f32x4
typedef __attribute__((ext_vector_type(2))) _Float16 half2v; // packed f16 pair (1 VGPR)

typedef unsigned short ushort_t;

__device__ inline short2 cvt2(float a, float b) {
    __hip_bfloat162 h = __float22bfloat162_rn(make_float2(a, b));
    union { __hip_bfloat162 h; short2 s; } u;
    u.h = h;
    return u.s;
}

__device__ inline short8 cvt8v(floatx4 x, floatx4 y) {
    union { short8 v; short2 s[4]; } u;
    u.s[0] = cvt2(x[0], x[1]);
    u.s[1] = cvt2(x[2], x[3]);
    u.s[2] = cvt2(y[0], y[1]);
    u.s[3] = cvt2(y[2], y[3]);
    return u.v;
}

__device__ inline ushort_t f2bfbits(float f) {
    unsigned u = __float_as_uint(f);
    u += 0x7FFFu + ((u >> 16) & 1u);   // round-to-nearest-even
    return (ushort_t)(u >> 16);
}

// ---------------- K1: ||v||^2 ----------------
__global__ void knorm(const float* __restrict__ v, float* __restrict__ ws0) {
    int t = blockIdx.x * 256 + threadIdx.x;     // 65536 threads, float2 each
    float2 x = ((const float2*)v)[t];
    float s = x.x * x.x + x.y * x.y;
    #pragma unroll
    for (int m = 1; m < 64; m <<= 1) s += __shfl_xor(s, m);
    __shared__ float ls[4];
    int w = threadIdx.x >> 6;
    if ((threadIdx.x & 63) == 0) ls[w] = s;
    __syncthreads();
    if (threadIdx.x == 0) atomicAdd(ws0, ls[0] + ls[1] + ls[2] + ls[3]);
}

// ---------------- K2: W=g*v/||v|| -> bf16 ; efeat -> bf16 (skip masked rows) ----------------
__global__ void kconv(const float* __restrict__ v, const float* __restrict__ g,
                      const float* __restrict__ ef, const float* __restrict__ ws0,
                      const int* __restrict__ nen,
                      ushort_t* __restrict__ wsW, ushort_t* __restrict__ wsE) {
    int bid = blockIdx.x;
    if (bid < 128) {
        int t = bid * 256 + threadIdx.x;        // 32768 threads * 4 elems = 131072
        float s = g[0] * rsqrtf(ws0[0]);
        float4 x = ((const float4*)v)[t];
        short2 a = cvt2(x.x * s, x.y * s);
        short2 b = cvt2(x.z * s, x.w * s);
        ushort4 o;
        o.x = (ushort_t)a.x; o.y = (ushort_t)a.y; o.z = (ushort_t)b.x; o.w = (ushort_t)b.y;
        ((ushort4*)wsW)[t] = o;
    } else {
        long t = (long)(bid - 128) * 256 + threadIdx.x;  // float4 index into efeat
        int row = (int)(t >> 6);                 // 64 float4 per 256-col row
        int n = row & (NEN - 1);
        int b = row >> 10;
        if (n < nen[b]) {                        // rows >= ne are never read downstream
            // efeat is read exactly once: nontemporal, don't pollute L2.
            floatx4 x = __builtin_nontemporal_load((const floatx4*)ef + t);
            short2 a = cvt2(x[0], x[1]);
            short2 c = cvt2(x[2], x[3]);
            ushort4 o;
            o.x = (ushort_t)a.x; o.y = (ushort_t)a.y; o.z = (ushort_t)c.x; o.w = (ushort_t)c.y;
            ((ushort4*)wsE)[t] = o;
        }
    }
}

// ---------------- K3+K4 fused: proj GEMM -> LDS -> attention softmax ----------------
// OCCUPANCY ROUND: 16 u-rows/block (grid 4096). Phase-2 live set halves:
// af 32 + bf 32 + acc(f16) 32 + psum/misc ~10 ≈ 105 unified regs => under the
// 128-reg cliff (m69: occupancy steps at 64/128/256) => 4 waves/SIMD = 16
// waves/CU (was 8). E double-buffer dropped (measured worth ~0-7us; TLP now
// covers E latency). LDS ~17KB => not the limiter. Balanced interleaved skip
// and the coalesced LDS epilogue are retained from rounds 3/9.
__launch_bounds__(256, 4)
__global__ void kfused(const float* __restrict__ A, const ushort_t* __restrict__ W,
                       const float* __restrict__ bias, const ushort_t* __restrict__ E,
                       const int* __restrict__ nen, float* __restrict__ out) {
    const int tid = threadIdx.x;
    const int w = tid >> 6, L = tid & 63;
    const int rA = L & 15, q = L >> 4;
    const int bid = blockIdx.x;
    const int b = bid >> 6;              // b-major: L2 locality on E
    const int ut = bid & 63;             // 0..63, 16 u-rows each
    const int ne = nen[b];

    __shared__ union ShMem {
        ushort_t Pl[16][264];            // proj tile (phase 1 -> af preload), 8.4 KB
        float    Cl[16][260];            // epilogue chunk staging, 16.6 KB
    } sh;
    __shared__ float lsum[4][16];

    // ---- Phase 1: GEMM proj[16x256] = relu(ufeat[16x512] @ W^T + b) ----
    {
        const long m0 = (long)b * NU + (long)ut * 16;
        floatx4 acc[4];
        #pragma unroll
        for (int n = 0; n < 4; n++) acc[n] = (floatx4){0.f, 0.f, 0.f, 0.f};

        const float* a0 = A + (m0 + rA) * UF + q * 8;
        const ushort_t* wp[4];
        #pragma unroll
        for (int n = 0; n < 4; n++) wp[n] = W + (long)(w * 64 + n * 16 + rA) * UF + q * 8;

        // prime the A pipeline (step 0)
        floatx4 x0 = *(const floatx4*)(a0);
        floatx4 y0 = *(const floatx4*)(a0 + 4);

        #pragma unroll 2
        for (int s = 0; s < 16; s++) {
            const int ko = s * 32;
            short8 wf[4];
            #pragma unroll
            for (int n = 0; n < 4; n++) wf[n] = *(const short8*)(wp[n] + ko);
            short8 af0 = cvt8v(x0, y0);
            if (s < 15) {                        // prefetch next step's A (HBM)
                x0 = *(const floatx4*)(a0 + ko + 32);
                y0 = *(const floatx4*)(a0 + ko + 36);
            }
            #pragma unroll
            for (int n = 0; n < 4; n++)
                acc[n] = __builtin_amdgcn_mfma_f32_16x16x32_bf16(af0, wf[n], acc[n], 0, 0, 0);
        }

        #pragma unroll
        for (int n = 0; n < 4; n++) {
            const int col = w * 64 + n * 16 + rA;
            const float bv = bias[col];
            #pragma unroll
            for (int i = 0; i < 4; i++) {
                float val = acc[n][i] + bv;
                val = fmaxf(val, 0.f);
                sh.Pl[q * 4 + i][col] = f2bfbits(val);
            }
        }
    }
    __syncthreads();

    // ---- Phase 2: attention ----
    // Preload A-frags from LDS (one-time); reused across all active n-steps.
    short8 af[8];
    #pragma unroll
    for (int s = 0; s < 8; s++)
        af[s] = *(const short8*)&sh.Pl[rA][s * 32 + q * 8];

    half2v acc[16][2];                   // exp values, f16-packed (RTNE)
    #pragma unroll
    for (int ns = 0; ns < 16; ns++) {
        acc[ns][0] = (half2v){(_Float16)0.f, (_Float16)0.f};
        acc[ns][1] = (half2v){(_Float16)0.f, (_Float16)0.f};
    }
    float psum[4] = {0.f, 0.f, 0.f, 0.f};

    // E rows for this wave's INTERLEAVED steps: row = ns*64 + w*16 + rA
    const ushort_t* erow = E + (long)(b * NEN + w * 16 + rA) * EF + q * 8;

    #pragma unroll
    for (int ns = 0; ns < 16; ns++) {
        const int col0 = ns * 64 + w * 16;
        if (col0 < ne) {                 // wave-uniform skip, balanced across waves
            const ushort_t* ep = erow + (long)ns * 64 * EF;
            short8 bf[8];
            #pragma unroll
            for (int s = 0; s < 8; s++) bf[s] = *(const short8*)(ep + s * 32);
            floatx4 c0 = (floatx4){0.f, 0.f, 0.f, 0.f};
            #pragma unroll
            for (int s = 0; s < 8; s++)
                c0 = __builtin_amdgcn_mfma_f32_16x16x32_bf16(af[s], bf[s], c0, 0, 0, 0);
            const int col = col0 + rA;
            const bool on = col < ne;    // boundary lanes: garbage E rows masked off
            #pragma unroll
            for (int i = 0; i < 4; i++) {
                float e0 = on ? __expf(c0[i] * 0.0625f) : 0.f;
                psum[i] += e0;
                c0[i] = e0;
            }
            acc[ns][0] = (half2v){(_Float16)c0[0], (_Float16)c0[1]};
            acc[ns][1] = (half2v){(_Float16)c0[2], (_Float16)c0[3]};
        }
    }

    // Row sums: reduce over the 16 lanes sharing q (cols), then across waves via LDS.
    #pragma unroll
    for (int i = 0; i < 4; i++) {
        float s = psum[i];
        s += __shfl_xor(s, 1);
        s += __shfl_xor(s, 2);
        s += __shfl_xor(s, 4);
        s += __shfl_xor(s, 8);
        psum[i] = s;
    }
    if (rA == 0) {
        #pragma unroll
        for (int i = 0; i < 4; i++) lsum[w][q * 4 + i] = psum[i];
    }
    __syncthreads();

    float inv[4];
    #pragma unroll
    for (int i = 0; i < 4; i++) {
        const int r = q * 4 + i;
        const float tot = lsum[0][r] + lsum[1][r] + lsum[2][r] + lsum[3][r];
        inv[i] = (ne > 0) ? (1.f / tot) : 0.f;
    }

    // ---- Coalesced epilogue: 4 chunks of 256 cols ----
    const float uni = 1.f / 1024.f;
    const long obase = ((long)(b * NU + ut * 16)) * (long)NEN;
    #pragma unroll
    for (int g = 0; g < 4; g++) {
        if (g > 0) __syncthreads();      // prior chunk's drain done before overwrite
        // stage: each lane writes its 16 final values for this chunk (2-way = free)
        #pragma unroll
        for (int ns2 = 0; ns2 < 4; ns2++) {
            const int ns = g * 4 + ns2;
            #pragma unroll
            for (int i = 0; i < 4; i++) {
                const float num = (float)acc[ns][i >> 1][i & 1];
                const float val = (ne == 0) ? uni : num * inv[i];
                sh.Cl[q * 4 + i][ns2 * 64 + w * 16 + rA] = val;
            }
        }
        __syncthreads();
        // drain: wave w writes rows w*4..w*4+3; 64 lanes x float4 = 1KB/instr
        #pragma unroll
        for (int j = 0; j < 4; j++) {
            const int r = w * 4 + j;
            floatx4 vv = *(const floatx4*)&sh.Cl[r][L * 4];
            __builtin_nontemporal_store(vv,
                (floatx4*)(out + obase + (long)r * NEN + g * 256 + L * 4));
        }
    }
}

extern "C" void kernel_launch(void* const* d_in, const int* in_sizes, int n_in,
                              void* d_out, int out_size, void* d_ws, size_t ws_size,
                              hipStream_t stream) {
    (void)in_sizes; (void)n_in; (void)out_size; (void)ws_size;
    const float* ufeat = (const float*)d_in[0];
    const float* efeat = (const float*)d_in[1];
    const int*   nen   = (const int*)d_in[2];
    const float* v     = (const float*)d_in[3];
    const float* g     = (const float*)d_in[4];
    const float* bias  = (const float*)d_in[5];
    float* out = (float*)d_out;

    float*    ws0 = (float*)d_ws;
    ushort_t* wsW = (ushort_t*)((char*)d_ws + 1024);        // 256 KB
    ushort_t* wsE = (ushort_t*)((char*)d_ws + (1u << 20));  // 32 MB

    hipMemsetAsync(d_ws, 0, 256, stream);
    knorm<<<256, 256, 0, stream>>>(v, ws0);
    kconv<<<16512, 256, 0, stream>>>(v, g, efeat, ws0, nen, wsW, wsE);
    kfused<<<4096, 256, 0, stream>>>(ufeat, wsW, bias, wsE, nen, out);
}